// Round 10
// baseline (166.806 us; speedup 1.0000x reference)
//
#include <hip/hip_runtime.h>

// Problem constants
#define BB_   16
#define CIN_  32
#define COUT_ 64
#define TT_   20      // depthwise time extent
#define NSTEP 22      // recurrence steps (pointwise pad grows T 20->22)
#define NPIX  1024    // 32*32
#define HW_   32

// ws layout (in floats)
// dw2[b][t][h][ci][32slots]: slot 0 = zeros (w-pad), slot s = dwconv(w=s-1)
#define N_DW2   10485760ULL                    // 16*20*32*32*32
#define OFF_DW2   0ULL
#define OFF_D     (OFF_DW2 + N_DW2)            // 4096 floats
#define OFF_INVN  (OFF_D + 4096ULL)            // 64 floats
#define OFF_CNT   (OFF_INVN + 64ULL)           // 22 uint32
#define OFF_DONE  (OFF_CNT + 24ULL)            // 1 uint32
#define WS_FLOATS (OFF_DONE + 8ULL)

#define DW_BLOCKS (BB_ * CIN_ * 4)             // 2048; block 2048 = dmat block
#define PS_ (32 * 32 * 32)                     // dw2 plane stride (floats / t)

// ---------------------------------------------------------------------------
// K1: depthwise 3x3x3 conv (validated stencil) writing dw2 DIRECTLY in the
// [b][t][h][ci][32] layout via LDS-staged w+1 shift (sbuf col 0 = zero pad).
// Block 2048: fp64 lateral matrix + gcnt/done zeroing.
// ---------------------------------------------------------------------------
__global__ __launch_bounds__(128)
void k_dw(const float* __restrict__ x, const float* __restrict__ wdw,
          const float* __restrict__ wpw, float* __restrict__ dw2,
          float* __restrict__ dmat, float* __restrict__ invn,
          unsigned* __restrict__ gcnt, unsigned* __restrict__ done) {
    const int blk = blockIdx.x;
    const int tid = threadIdx.x;

    if (blk == DW_BLOCKS) {                    // ---- dmat side-block
        __shared__ double S[32];
        if (tid < NSTEP) gcnt[tid] = 0u;
        if (tid == NSTEP) *done = 0u;
        if (tid < 32) {
            double s = 0.0;
            for (int k = 0; k < 27; ++k) { double v = (double)wdw[tid * 27 + k]; s += v * v; }
            S[tid] = s;
        }
        __syncthreads();
        for (int e = tid; e < 4096; e += 128) {
            const int a = e >> 6, f = e & 63;
            double acc = 0.0;
            for (int ci = 0; ci < 32; ++ci)
                acc += (double)wpw[a * 32 + ci] * (double)wpw[f * 32 + ci] * S[ci];
            dmat[e] = (float)acc;
            if (a == f) invn[a] = (float)(1.0 / (acc + 1e-8));
        }
        return;
    }

    const int t4 = blk & 3;
    const int ci = (blk >> 2) & 31;
    const int b  = blk >> 7;
    __shared__ float pl[3][34][35];
    __shared__ float sbuf[32][34];             // col 0 = zero pad; col s = acc(w=s-1)

    float w[27];
#pragma unroll
    for (int k = 0; k < 27; ++k) w[k] = wdw[ci * 27 + k];

    for (int i = tid; i < 3 * 34 * 35; i += 128) (&pl[0][0][0])[i] = 0.f;
    for (int i = tid; i < 32 * 34; i += 128) (&sbuf[0][0])[i] = 0.f;   // incl. col 0
    __syncthreads();

    const float* xb = x + (size_t)(b * 32 + ci) * TT_ * NPIX;
    const int lr = tid >> 2;            // 0..31 row (h)
    const int lc = (tid & 3) * 8;       // col group of 8

    auto load_plane = [&](int p, int slot) {
        const float* s = xb + (size_t)p * NPIX + lr * 32 + lc;
        float4 v0 = *(const float4*)s;
        float4 v1 = *(const float4*)(s + 4);
        float* d = &pl[slot][1 + lr][1 + lc];
        d[0] = v0.x; d[1] = v0.y; d[2] = v0.z; d[3] = v0.w;
        d[4] = v1.x; d[5] = v1.y; d[6] = v1.z; d[7] = v1.w;
    };
    auto zero_plane = [&](int slot) {
        float* d = &pl[slot][1 + lr][1 + lc];
#pragma unroll
        for (int j = 0; j < 8; ++j) d[j] = 0.f;
    };
    // store sbuf (plane tt) -> dw2, shifted layout, fully coalesced
    auto store_shifted = [&](int tt) {
        const float* src = &sbuf[lr][lc];      // slots lc..lc+7 (col s = value of slot s)
        float4 o0 = make_float4(src[0], src[1], src[2], src[3]);
        float4 o1 = make_float4(src[4], src[5], src[6], src[7]);
        float* dst = dw2 + (((size_t)(b * TT_ + tt) * 32 + lr) * 32 + ci) * 32 + lc;
        *(float4*)dst       = o0;
        *(float4*)(dst + 4) = o1;
    };

    const int T0 = t4 * 5;
    if (T0 > 0) load_plane(T0 - 1, (T0 - 1) % 3);
    load_plane(T0, T0 % 3);

    const int hd = lr, wd0 = lc;
    const float* base = &pl[0][0][0];

    for (int t = T0; t < T0 + 5; ++t) {
        __syncthreads();                       // prior pl reads + sbuf writes visible
        const int pnext = t + 1;
        if (pnext < TT_) load_plane(pnext, pnext % 3);
        else             zero_plane(pnext % 3);
        if (t > T0) store_shifted(t - 1);      // sbuf holds plane t-1
        __syncthreads();                       // loads visible; sbuf reads done

        const int sm1 = (t + 2) % 3, s0 = t % 3, sp1 = (t + 1) % 3;
        float acc[8] = {0.f,0.f,0.f,0.f,0.f,0.f,0.f,0.f};
#pragma unroll
        for (int kt = 0; kt < 3; ++kt) {
            const int slot = (kt == 0) ? sm1 : (kt == 1) ? s0 : sp1;
            const float* Pp = base + slot * (34 * 35);
#pragma unroll
            for (int kh = 0; kh < 3; ++kh) {
                const float* row = Pp + (hd + kh) * 35 + wd0;
                float r[10];
#pragma unroll
                for (int m = 0; m < 10; ++m) r[m] = row[m];
#pragma unroll
                for (int kw = 0; kw < 3; ++kw) {
                    const float wv = w[(kt * 3 + kh) * 3 + kw];
#pragma unroll
                    for (int j = 0; j < 8; ++j) acc[j] = fmaf(wv, r[j + kw], acc[j]);
                }
            }
        }
        // stage into sbuf at col w+1 (shift); col 0 stays zero
#pragma unroll
        for (int j = 0; j < 8; ++j) sbuf[hd][wd0 + 1 + j] = acc[j];
    }
    __syncthreads();
    store_shifted(T0 + 4);                     // final staged plane
}

// ---------------------------------------------------------------------------
// K2: ballot-wave fused pointwise conv + recurrence (R5 loop structure).
// dw2 reads: 32x wave-uniform float2 loads per step ([ci][slot] layout).
// fmaf chains ci-ascending -> bit-exact. Last block computes losses (ticket).
// ---------------------------------------------------------------------------
__global__ __launch_bounds__(512)
void k_recur(const float* __restrict__ dw2, const float* __restrict__ wpw,
             const float* __restrict__ dmat, const float* __restrict__ invn_g,
             const float* __restrict__ beta_g, const float* __restrict__ bvec,
             float* __restrict__ out, unsigned* __restrict__ gcnt,
             unsigned* __restrict__ done, int out_size) {
    const int blk = blockIdx.x;
    const int whalf = blk & 1;
    const int h = (blk >> 1) & 31;
    const int b = blk >> 6;
    const int tid = threadIdx.x;
    const int lane = tid & 63;
    const int co = lane;
    const int wid = __builtin_amdgcn_readfirstlane(tid >> 6);   // 0..7
    const int w0 = whalf * 16 + wid * 2;        // global w of wave's pixel 0

    __shared__ float d_lds[4096];
    __shared__ unsigned long long msk[NSTEP][16];

    for (int i = tid; i < 4096; i += 512) d_lds[i] = dmat[i];
    {
        unsigned long long* mp = &msk[0][0];
        for (int i = tid; i < NSTEP * 16; i += 512) mp[i] = 0ull;
    }

    const float beta_v = beta_g[0];
    const float omb = 1.0f - beta_v;
    const float invn = invn_g[co];
    const float bth  = bvec[co];

    float wa[32];
#pragma unroll
    for (int ci = 0; ci < 32; ++ci) wa[ci] = wpw[co * 32 + ci];

    float mem0 = 0.f, mem1 = 0.f;
    unsigned long long m0p = 0ull, m1p = 0ull;

    // t = 0 plane: all spikes zero (inp=0, mem=0, -b<0)
    {
        const int zco = tid >> 3, zw = (tid & 7) * 2;
        *(float2*)(out + ((size_t)(b * 64 + zco) * NSTEP) * NPIX + h * 32 + whalf * 16 + zw)
            = make_float2(0.f, 0.f);
    }
    __syncthreads();   // d_lds + zeroed bitplanes visible

    // wave-uniform base: dw2 plane (t-1), row (h-1), pixel-pair w0 (valid iff h>=1)
    const size_t rbase = ((size_t)(b * TT_) * 32 + (h - 1)) * (32 * 32) + w0;
    const bool hok = (h >= 1);

    float2 A[32];                   // wave-uniform pairs (slot w0, w0+1) per ci
    if (hok) {                      // preload step t=1 (plane 0)
        const float* rp = dw2 + rbase;
#pragma unroll
        for (int ci = 0; ci < 32; ++ci) A[ci] = *(const float2*)(rp + ci * 32);
    }

    for (int t = 1; t < NSTEP; ++t) {
        float inp0 = 0.f, inp1 = 0.f;
        if (hok && t <= TT_) {      // consume A (ci-ascending chains, bit-exact)
#pragma unroll
            for (int ci = 0; ci < 32; ++ci) {
                inp0 = fmaf(wa[ci], A[ci].x, inp0);
                inp1 = fmaf(wa[ci], A[ci].y, inp1);
            }
        }
        // reissue loads for step t+1 (hidden under reset/ballot tail)
        if (hok && t < TT_) {
            const float* rp = dw2 + rbase + (size_t)t * PS_;
#pragma unroll
            for (int ci = 0; ci < 32; ++ci) A[ci] = *(const float2*)(rp + ci * 32);
        }

        // lateral reset from previous step's masks (sparse bit iteration)
        float rst0 = 0.f, rst1 = 0.f;
        unsigned long long mm = m0p;
        while (mm) { const int a = __builtin_ctzll(mm); mm &= mm - 1; rst0 += d_lds[a * 64 + co]; }
        mm = m1p;
        while (mm) { const int a = __builtin_ctzll(mm); mm &= mm - 1; rst1 += d_lds[a * 64 + co]; }

        // membrane update + spike (same expression order as validated rounds)
        const float u0 = (mem0 - rst0) * beta_v;
        mem0 = u0 + inp0 * omb;
        const bool s0 = (mem0 * invn - bth) > 0.f;
        const float u1 = (mem1 - rst1) * beta_v;
        mem1 = u1 + inp1 * omb;
        const bool s1 = (mem1 * invn - bth) > 0.f;

        m0p = __ballot(s0);
        m1p = __ballot(s1);
        const int wl = wid * 2;
        if (lane == 0) { msk[t][wl] = m0p; msk[t][wl + 1] = m1p; }
    }
    __syncthreads();

    // exact per-t spike counts (integer, deterministic)
    if (tid < NSTEP) {
        unsigned c = 0;
        for (int w = 0; w < 16; ++w) c += (unsigned)__popcll(msk[tid][w]);
        if (c) atomicAdd(&gcnt[tid], c);
    }

    // coalesced bit->float stores: 1408 (co,t) rows x 16 w (64B, sector-exact)
    const int wl = tid & 15;
    for (int it = 0; it < 44; ++it) {
        const int r = it * 32 + (tid >> 4);         // 0..1407
        const int tt = r >> 6, cc = r & 63;
        const unsigned long long wv = msk[tt][wl];
        const float sv = (float)((wv >> cc) & 1ull);
        out[((size_t)(b * 64 + cc) * NSTEP + tt) * NPIX + h * 32 + whalf * 16 + wl] = sv;
    }

    // last-block-out: compute losses (integer atomics -> order-independent)
    __syncthreads();                 // all this block's mem ops drained per-wave
    if (tid == 0) {
        __threadfence();
        const unsigned old = atomicAdd(done, 1u);
        if (old == (BB_ * HW_ * 2) - 1) {
            unsigned long long tot = 0; unsigned mx = 0;
            for (int t = 0; t < NSTEP; ++t) {
                const unsigned c = atomicAdd(&gcnt[t], 0u);   // coherent read
                tot += c; if (c > mx) mx = c;
            }
            const long long nspk = (long long)out_size - 2;   // 23,068,672
            out[out_size - 2] = (float)(0.5 * ((double)tot / (double)nspk));
            out[out_size - 1] = (float)((double)mx / 1048576.0);
            atomicExch(done, 0u);    // replay-safe reset
        }
    }
}

extern "C" void kernel_launch(void* const* d_in, const int* in_sizes, int n_in,
                              void* d_out, int out_size, void* d_ws, size_t ws_size,
                              hipStream_t stream) {
    const float* x    = (const float*)d_in[0];
    const float* wdw  = (const float*)d_in[1];
    const float* wpw  = (const float*)d_in[2];
    const float* beta = (const float*)d_in[3];
    const float* bvec = (const float*)d_in[4];
    float* out = (float*)d_out;
    float* ws  = (float*)d_ws;

    if (ws_size < WS_FLOATS * sizeof(float)) return;

    float* dw2   = ws + OFF_DW2;
    float* dmat  = ws + OFF_D;
    float* invn  = ws + OFF_INVN;
    unsigned* gcnt = (unsigned*)(ws + OFF_CNT);
    unsigned* done = (unsigned*)(ws + OFF_DONE);

    k_dw   <<<DW_BLOCKS + 1, 128, 0, stream>>>(x, wdw, wpw, dw2, dmat, invn, gcnt, done);
    k_recur<<<BB_ * HW_ * 2, 512, 0, stream>>>(dw2, wpw, dmat, invn, beta, bvec, out,
                                               gcnt, done, out_size);
}

// Round 11
// 135.306 us; speedup vs baseline: 1.2328x; 1.2328x over previous
//
#include <hip/hip_runtime.h>

// Problem constants
#define BB_   16
#define CIN_  32
#define COUT_ 64
#define TT_   20      // depthwise time extent
#define NSTEP 22      // recurrence steps (pointwise pad grows T 20->22)
#define NPIX  1024    // 32*32
#define HW_   32

typedef float f32x16 __attribute__((ext_vector_type(16)));

// ws layout (in floats)
#define N_DWOUT 10485760ULL                    // 16*32*20*1024 [ci-major]
#define N_DW2   10485760ULL                    // 16*20*32*1024 [slot][ci] transposed
#define OFF_DWOUT 0ULL
#define OFF_DW2   (OFF_DWOUT + N_DWOUT)
#define OFF_D     (OFF_DW2 + N_DW2)            // 4096 floats
#define OFF_INVN  (OFF_D + 4096ULL)            // 64 floats
#define OFF_CNT   (OFF_INVN + 64ULL)           // 22 uint32
#define OFF_DONE  (OFF_CNT + 24ULL)            // 1 uint32
#define WS_FLOATS (OFF_DONE + 8ULL)

#define DW_BLOCKS (BB_ * CIN_ * 4)             // 2048; block 2048 = dmat block
#define NRECUR   (BB_ * HW_ * 2)               // 1024 recurrence blocks

// ---------------------------------------------------------------------------
// K1: depthwise 3x3x3 conv (R5 verbatim) + dmat side-block (validated R6):
// blocks 0..2047 produce dwout[b][ci][t][h][w]; block 2048 computes the fp64
// lateral matrix, inv_norm, and zeroes gcnt/done.
// ---------------------------------------------------------------------------
__global__ __launch_bounds__(128)
void k_depthwise(const float* __restrict__ x, const float* __restrict__ wdw,
                 const float* __restrict__ wpw, float* __restrict__ dwout,
                 float* __restrict__ dmat, float* __restrict__ invn,
                 unsigned* __restrict__ gcnt, unsigned* __restrict__ done) {
    const int blk = blockIdx.x;
    const int tid = threadIdx.x;

    if (blk == DW_BLOCKS) {                    // ---- dmat block (128 threads)
        __shared__ double S[32];
        if (tid < NSTEP) gcnt[tid] = 0u;
        if (tid == NSTEP) *done = 0u;
        if (tid < 32) {
            double s = 0.0;
            for (int k = 0; k < 27; ++k) { double v = (double)wdw[tid * 27 + k]; s += v * v; }
            S[tid] = s;
        }
        __syncthreads();
        for (int e = tid; e < 4096; e += 128) {
            const int a = e >> 6, f = e & 63;
            double acc = 0.0;
            for (int ci = 0; ci < 32; ++ci)
                acc += (double)wpw[a * 32 + ci] * (double)wpw[f * 32 + ci] * S[ci];
            dmat[e] = (float)acc;
            if (a == f) invn[a] = (float)(1.0 / (acc + 1e-8));
        }
        return;
    }

    const int t4 = blk & 3;
    const int ci = (blk >> 2) & 31;
    const int b  = blk >> 7;
    __shared__ float pl[3][34][35];

    float w[27];
#pragma unroll
    for (int k = 0; k < 27; ++k) w[k] = wdw[ci * 27 + k];

    for (int i = tid; i < 3 * 34 * 35; i += 128) (&pl[0][0][0])[i] = 0.f;
    __syncthreads();

    const float* xb = x + (size_t)(b * 32 + ci) * TT_ * NPIX;
    const int lr = tid >> 2;
    const int lc = (tid & 3) * 8;

    auto load_plane = [&](int p, int slot) {
        const float* s = xb + (size_t)p * NPIX + lr * 32 + lc;
        float4 v0 = *(const float4*)s;
        float4 v1 = *(const float4*)(s + 4);
        float* d = &pl[slot][1 + lr][1 + lc];
        d[0] = v0.x; d[1] = v0.y; d[2] = v0.z; d[3] = v0.w;
        d[4] = v1.x; d[5] = v1.y; d[6] = v1.z; d[7] = v1.w;
    };
    auto zero_plane = [&](int slot) {
        float* d = &pl[slot][1 + lr][1 + lc];
#pragma unroll
        for (int j = 0; j < 8; ++j) d[j] = 0.f;
    };

    const int T0 = t4 * 5;
    if (T0 > 0) load_plane(T0 - 1, (T0 - 1) % 3);
    load_plane(T0, T0 % 3);

    const int hd = lr, wd0 = lc;
    const float* base = &pl[0][0][0];

    for (int t = T0; t < T0 + 5; ++t) {
        __syncthreads();
        const int pnext = t + 1;
        if (pnext < TT_) load_plane(pnext, pnext % 3);
        else             zero_plane(pnext % 3);
        __syncthreads();

        const int sm1 = (t + 2) % 3, s0 = t % 3, sp1 = (t + 1) % 3;
        float acc[8] = {0.f,0.f,0.f,0.f,0.f,0.f,0.f,0.f};
#pragma unroll
        for (int kt = 0; kt < 3; ++kt) {
            const int slot = (kt == 0) ? sm1 : (kt == 1) ? s0 : sp1;
            const float* Pp = base + slot * (34 * 35);
#pragma unroll
            for (int kh = 0; kh < 3; ++kh) {
                const float* row = Pp + (hd + kh) * 35 + wd0;
                float r[10];
#pragma unroll
                for (int m = 0; m < 10; ++m) r[m] = row[m];
#pragma unroll
                for (int kw = 0; kw < 3; ++kw) {
                    const float wv = w[(kt * 3 + kh) * 3 + kw];
#pragma unroll
                    for (int j = 0; j < 8; ++j) acc[j] = fmaf(wv, r[j + kw], acc[j]);
                }
            }
        }
        float* dst = dwout + ((size_t)(b * 32 + ci) * TT_ + t) * NPIX + hd * 32 + wd0;
        *(float4*)dst       = make_float4(acc[0], acc[1], acc[2], acc[3]);
        *(float4*)(dst + 4) = make_float4(acc[4], acc[5], acc[6], acc[7]);
    }
}

// ---------------------------------------------------------------------------
// K2: transpose dwout -> dw2 [b][t][h][slot=w+1][ci], slot 0 = zeros.
// R5 verbatim. The [slot][ci] layout is LOAD-BEARING: it makes k_recur's
// per-step operands 4 contiguous s_load_dwordx16 (R10 showed 32x 8B scalar
// loads at 128B stride are 5x slower - scalar-cache thrash).
// ---------------------------------------------------------------------------
__global__ __launch_bounds__(256)
void k_transpose(const float* __restrict__ dwout, float* __restrict__ dw2) {
    const int blk = blockIdx.x;            // (b*20 + t)*8 + hq
    const int hq = blk & 7;
    const int bt = blk >> 3;
    const int t  = bt % 20;
    const int b  = bt / 20;
    const int tid = threadIdx.x;
    __shared__ float lt[32][33];
    const int wsrc = tid & 31, cg = tid >> 5;

    for (int hh = 0; hh < 4; ++hh) {
        const int h = hq * 4 + hh;
#pragma unroll
        for (int cc = 0; cc < 4; ++cc) {
            const int ci = cc * 8 + cg;
            lt[wsrc][ci] = dwout[((size_t)(b * 32 + ci) * TT_ + t) * NPIX + h * 32 + wsrc];
        }
        __syncthreads();
        float* drow = dw2 + ((size_t)(b * TT_ + t) * 32 + h) * NPIX;
#pragma unroll
        for (int ss = 0; ss < 4; ++ss) {
            const int slot = ss * 8 + cg;
            drow[slot * 32 + wsrc] = (slot == 0) ? 0.f : lt[slot - 1][wsrc];
        }
        __syncthreads();
    }
}

// ---------------------------------------------------------------------------
// K3: ballot-wave fused pointwise conv + recurrence (R5 verbatim: barrier-free
// t-loop, f32x16 scalar operands, terminal 64B-sector store phase) + losses
// via last-block-out ticket (validated R10).
// ---------------------------------------------------------------------------
__global__ __launch_bounds__(512)
void k_recur(const float* __restrict__ dw2, const float* __restrict__ wpw,
             const float* __restrict__ dmat, const float* __restrict__ invn_g,
             const float* __restrict__ beta_g, const float* __restrict__ bvec,
             float* __restrict__ out, unsigned* __restrict__ gcnt,
             unsigned* __restrict__ done, int out_size) {
    const int blk = blockIdx.x;
    const int whalf = blk & 1;
    const int h = (blk >> 1) & 31;
    const int b = blk >> 6;
    const int tid = threadIdx.x;
    const int lane = tid & 63;
    const int co = lane;
    const int wid = __builtin_amdgcn_readfirstlane(tid >> 6);   // 0..7
    const int w0 = whalf * 16 + wid * 2;        // global w of wave's pixel 0

    __shared__ float d_lds[4096];
    __shared__ unsigned long long msk[NSTEP][16];

    for (int i = tid; i < 4096; i += 512) d_lds[i] = dmat[i];
    {
        unsigned long long* mp = &msk[0][0];
        for (int i = tid; i < NSTEP * 16; i += 512) mp[i] = 0ull;
    }

    const float beta_v = beta_g[0];
    const float omb = 1.0f - beta_v;
    const float invn = invn_g[co];
    const float bth  = bvec[co];

    float wa[32];
#pragma unroll
    for (int ci = 0; ci < 32; ++ci) wa[ci] = wpw[co * 32 + ci];

    float mem0 = 0.f, mem1 = 0.f;
    unsigned long long m0p = 0ull, m1p = 0ull;

    // t = 0 plane: all spikes zero (inp=0, mem=0, -b<0). 512 thr x float2 = 4KB.
    {
        const int zco = tid >> 3, zw = (tid & 7) * 2;
        *(float2*)(out + ((size_t)(b * 64 + zco) * NSTEP) * NPIX + h * 32 + whalf * 16 + zw)
            = make_float2(0.f, 0.f);
    }

    __syncthreads();   // d_lds + zeroed bitplanes visible

    // wave-uniform base into dw2 (b, h-1, slots w0..w0+1); valid iff h>=1
    const int base0 = ((b * TT_) * 32 + (h - 1)) * NPIX + w0 * 32;
    const bool hok = (h >= 1);

    f32x16 A0, A1, A2, A3;          // wave-uniform -> SGPRs
    if (hok) {                      // preload step t=1 (plane 0)
        const float* wrow = dw2 + (size_t)base0;
        A0 = *(const f32x16*)(wrow);
        A1 = *(const f32x16*)(wrow + 16);
        A2 = *(const f32x16*)(wrow + 32);
        A3 = *(const f32x16*)(wrow + 48);
    }

    for (int t = 1; t < NSTEP; ++t) {
        float inp0 = 0.f, inp1 = 0.f;
        if (hok && t <= TT_) {      // consume current A set (ci-ascending, bit-exact)
#pragma unroll
            for (int ci = 0; ci < 16; ++ci) {
                inp0 = fmaf(wa[ci], A0[ci], inp0);
                inp1 = fmaf(wa[ci], A2[ci], inp1);
            }
#pragma unroll
            for (int ci = 0; ci < 16; ++ci) {
                inp0 = fmaf(wa[16 + ci], A1[ci], inp0);
                inp1 = fmaf(wa[16 + ci], A3[ci], inp1);
            }
        }
        // reissue loads for step t+1 into the same registers (hidden under tail)
        if (hok && t < TT_) {
            const float* wrow = dw2 + (size_t)base0 + (size_t)t * (32 * NPIX);
            A0 = *(const f32x16*)(wrow);
            A1 = *(const f32x16*)(wrow + 16);
            A2 = *(const f32x16*)(wrow + 32);
            A3 = *(const f32x16*)(wrow + 48);
        }

        // lateral reset from previous step's masks (sparse bit iteration)
        float rst0 = 0.f, rst1 = 0.f;
        unsigned long long mm = m0p;
        while (mm) { const int a = __builtin_ctzll(mm); mm &= mm - 1; rst0 += d_lds[a * 64 + co]; }
        mm = m1p;
        while (mm) { const int a = __builtin_ctzll(mm); mm &= mm - 1; rst1 += d_lds[a * 64 + co]; }

        // membrane update + spike (same expression order as validated rounds)
        const float u0 = (mem0 - rst0) * beta_v;
        mem0 = u0 + inp0 * omb;
        const bool s0 = (mem0 * invn - bth) > 0.f;
        const float u1 = (mem1 - rst1) * beta_v;
        mem1 = u1 + inp1 * omb;
        const bool s1 = (mem1 * invn - bth) > 0.f;

        m0p = __ballot(s0);
        m1p = __ballot(s1);
        const int wl = wid * 2;
        if (lane == 0) { msk[t][wl] = m0p; msk[t][wl + 1] = m1p; }
    }
    __syncthreads();

    // exact per-t spike counts (integer, deterministic)
    if (tid < NSTEP) {
        unsigned c = 0;
        for (int w = 0; w < 16; ++w) c += (unsigned)__popcll(msk[tid][w]);
        if (c) atomicAdd(&gcnt[tid], c);
    }

    // coalesced bit->float stores: 1408 (co,t) rows x 16 w (64B, sector-exact)
    const int wl = tid & 15;
    for (int it = 0; it < 44; ++it) {
        const int r = it * 32 + (tid >> 4);         // 0..1407
        const int tt = r >> 6, cc = r & 63;
        const unsigned long long wv = msk[tt][wl];
        const float sv = (float)((wv >> cc) & 1ull);
        out[((size_t)(b * 64 + cc) * NSTEP + tt) * NPIX + h * 32 + whalf * 16 + wl] = sv;
    }

    // last-block-out: losses from exact integer spike counts (validated R10)
    __syncthreads();
    if (tid == 0) {
        __threadfence();
        const unsigned old = atomicAdd(done, 1u);
        if (old == NRECUR - 1) {
            unsigned long long tot = 0; unsigned mx = 0;
            for (int t = 0; t < NSTEP; ++t) {
                const unsigned c = atomicAdd(&gcnt[t], 0u);   // coherent read
                tot += c; if (c > mx) mx = c;
            }
            const long long nspk = (long long)out_size - 2;   // 23,068,672
            out[out_size - 2] = (float)(0.5 * ((double)tot / (double)nspk));
            out[out_size - 1] = (float)((double)mx / 1048576.0);
            atomicExch(done, 0u);    // replay-safe reset
        }
    }
}

extern "C" void kernel_launch(void* const* d_in, const int* in_sizes, int n_in,
                              void* d_out, int out_size, void* d_ws, size_t ws_size,
                              hipStream_t stream) {
    const float* x    = (const float*)d_in[0];
    const float* wdw  = (const float*)d_in[1];
    const float* wpw  = (const float*)d_in[2];
    const float* beta = (const float*)d_in[3];
    const float* bvec = (const float*)d_in[4];
    float* out = (float*)d_out;
    float* ws  = (float*)d_ws;

    if (ws_size < WS_FLOATS * sizeof(float)) return;

    float* dwout = ws + OFF_DWOUT;
    float* dw2   = ws + OFF_DW2;
    float* dmat  = ws + OFF_D;
    float* invn  = ws + OFF_INVN;
    unsigned* gcnt = (unsigned*)(ws + OFF_CNT);
    unsigned* done = (unsigned*)(ws + OFF_DONE);

    k_depthwise<<<DW_BLOCKS + 1, 128, 0, stream>>>(x, wdw, wpw, dwout, dmat, invn, gcnt, done);
    k_transpose<<<BB_ * TT_ * 8, 256, 0, stream>>>(dwout, dw2);
    k_recur    <<<NRECUR, 512, 0, stream>>>(dw2, wpw, dmat, invn, beta, bvec, out,
                                            gcnt, done, out_size);
}

// Round 12
// 102.033 us; speedup vs baseline: 1.6348x; 1.3261x over previous
//
#include <hip/hip_runtime.h>

// Problem constants
#define BB_   16
#define CIN_  32
#define COUT_ 64
#define TT_   20      // depthwise time extent
#define NSTEP 22      // recurrence steps (pointwise pad grows T 20->22)
#define NPIX  1024    // 32*32
#define HW_   32

typedef float f32x16 __attribute__((ext_vector_type(16)));

// ws layout (in floats)
#define N_DWOUT 10485760ULL                    // 16*32*20*1024 [ci-major]
#define N_DW2   10485760ULL                    // 16*20*32*1024 [slot][ci] transposed
#define OFF_DWOUT 0ULL
#define OFF_DW2   (OFF_DWOUT + N_DWOUT)
#define OFF_D     (OFF_DW2 + N_DW2)            // 4096 floats
#define OFF_INVN  (OFF_D + 4096ULL)            // 64 floats
#define OFF_CNT   (OFF_INVN + 64ULL)           // 22 uint32
#define WS_FLOATS (OFF_CNT + 32ULL)

#define DW_BLOCKS (BB_ * CIN_ * 4)             // 2048; block 2048 = dmat block

// ---------------------------------------------------------------------------
// K1: depthwise 3x3x3 conv (R5 verbatim) + dmat side-block: blocks 0..2047
// produce dwout[b][ci][t][h][w]; block 2048 computes the fp64 lateral matrix,
// inv_norm, and zeroes gcnt. NOTE: no device fences anywhere — kernel
// boundaries are the only (cheap) global sync (R11 lesson: per-block
// __threadfence costs ~40us across 1024 blocks on 8 non-coherent XCD L2s).
// ---------------------------------------------------------------------------
__global__ __launch_bounds__(128)
void k_depthwise(const float* __restrict__ x, const float* __restrict__ wdw,
                 const float* __restrict__ wpw, float* __restrict__ dwout,
                 float* __restrict__ dmat, float* __restrict__ invn,
                 unsigned* __restrict__ gcnt) {
    const int blk = blockIdx.x;
    const int tid = threadIdx.x;

    if (blk == DW_BLOCKS) {                    // ---- dmat block (128 threads)
        __shared__ double S[32];
        if (tid < NSTEP) gcnt[tid] = 0u;
        if (tid < 32) {
            double s = 0.0;
            for (int k = 0; k < 27; ++k) { double v = (double)wdw[tid * 27 + k]; s += v * v; }
            S[tid] = s;
        }
        __syncthreads();
        for (int e = tid; e < 4096; e += 128) {
            const int a = e >> 6, f = e & 63;
            double acc = 0.0;
            for (int ci = 0; ci < 32; ++ci)
                acc += (double)wpw[a * 32 + ci] * (double)wpw[f * 32 + ci] * S[ci];
            dmat[e] = (float)acc;
            if (a == f) invn[a] = (float)(1.0 / (acc + 1e-8));
        }
        return;
    }

    const int t4 = blk & 3;
    const int ci = (blk >> 2) & 31;
    const int b  = blk >> 7;
    __shared__ float pl[3][34][35];

    float w[27];
#pragma unroll
    for (int k = 0; k < 27; ++k) w[k] = wdw[ci * 27 + k];

    for (int i = tid; i < 3 * 34 * 35; i += 128) (&pl[0][0][0])[i] = 0.f;
    __syncthreads();

    const float* xb = x + (size_t)(b * 32 + ci) * TT_ * NPIX;
    const int lr = tid >> 2;
    const int lc = (tid & 3) * 8;

    auto load_plane = [&](int p, int slot) {
        const float* s = xb + (size_t)p * NPIX + lr * 32 + lc;
        float4 v0 = *(const float4*)s;
        float4 v1 = *(const float4*)(s + 4);
        float* d = &pl[slot][1 + lr][1 + lc];
        d[0] = v0.x; d[1] = v0.y; d[2] = v0.z; d[3] = v0.w;
        d[4] = v1.x; d[5] = v1.y; d[6] = v1.z; d[7] = v1.w;
    };
    auto zero_plane = [&](int slot) {
        float* d = &pl[slot][1 + lr][1 + lc];
#pragma unroll
        for (int j = 0; j < 8; ++j) d[j] = 0.f;
    };

    const int T0 = t4 * 5;
    if (T0 > 0) load_plane(T0 - 1, (T0 - 1) % 3);
    load_plane(T0, T0 % 3);

    const int hd = lr, wd0 = lc;
    const float* base = &pl[0][0][0];

    for (int t = T0; t < T0 + 5; ++t) {
        __syncthreads();
        const int pnext = t + 1;
        if (pnext < TT_) load_plane(pnext, pnext % 3);
        else             zero_plane(pnext % 3);
        __syncthreads();

        const int sm1 = (t + 2) % 3, s0 = t % 3, sp1 = (t + 1) % 3;
        float acc[8] = {0.f,0.f,0.f,0.f,0.f,0.f,0.f,0.f};
#pragma unroll
        for (int kt = 0; kt < 3; ++kt) {
            const int slot = (kt == 0) ? sm1 : (kt == 1) ? s0 : sp1;
            const float* Pp = base + slot * (34 * 35);
#pragma unroll
            for (int kh = 0; kh < 3; ++kh) {
                const float* row = Pp + (hd + kh) * 35 + wd0;
                float r[10];
#pragma unroll
                for (int m = 0; m < 10; ++m) r[m] = row[m];
#pragma unroll
                for (int kw = 0; kw < 3; ++kw) {
                    const float wv = w[(kt * 3 + kh) * 3 + kw];
#pragma unroll
                    for (int j = 0; j < 8; ++j) acc[j] = fmaf(wv, r[j + kw], acc[j]);
                }
            }
        }
        float* dst = dwout + ((size_t)(b * 32 + ci) * TT_ + t) * NPIX + hd * 32 + wd0;
        *(float4*)dst       = make_float4(acc[0], acc[1], acc[2], acc[3]);
        *(float4*)(dst + 4) = make_float4(acc[4], acc[5], acc[6], acc[7]);
    }
}

// ---------------------------------------------------------------------------
// K2: transpose dwout -> dw2 [b][t][h][slot=w+1][ci], slot 0 = zeros.
// R5 verbatim. [slot][ci] layout is LOAD-BEARING: k_recur's per-step operands
// become 4 contiguous s_load_dwordx16 (R10: 32x 8B strided scalar loads are
// 3x slower - scalar-cache thrash).
// ---------------------------------------------------------------------------
__global__ __launch_bounds__(256)
void k_transpose(const float* __restrict__ dwout, float* __restrict__ dw2) {
    const int blk = blockIdx.x;            // (b*20 + t)*8 + hq
    const int hq = blk & 7;
    const int bt = blk >> 3;
    const int t  = bt % 20;
    const int b  = bt / 20;
    const int tid = threadIdx.x;
    __shared__ float lt[32][33];
    const int wsrc = tid & 31, cg = tid >> 5;

    for (int hh = 0; hh < 4; ++hh) {
        const int h = hq * 4 + hh;
#pragma unroll
        for (int cc = 0; cc < 4; ++cc) {
            const int ci = cc * 8 + cg;
            lt[wsrc][ci] = dwout[((size_t)(b * 32 + ci) * TT_ + t) * NPIX + h * 32 + wsrc];
        }
        __syncthreads();
        float* drow = dw2 + ((size_t)(b * TT_ + t) * 32 + h) * NPIX;
#pragma unroll
        for (int ss = 0; ss < 4; ++ss) {
            const int slot = ss * 8 + cg;
            drow[slot * 32 + wsrc] = (slot == 0) ? 0.f : lt[slot - 1][wsrc];
        }
        __syncthreads();
    }
}

// ---------------------------------------------------------------------------
// K3: ballot-wave fused pointwise conv + recurrence — R5 VERBATIM.
// Barrier-free t-loop, 4x s_load_dwordx16 wave-uniform operands with same-reg
// reissue, sparse-mask lateral reset, terminal 64B-sector bit->float stores.
// NO tail fence/ticket (R11 lesson).
// ---------------------------------------------------------------------------
__global__ __launch_bounds__(512)
void k_recur(const float* __restrict__ dw2, const float* __restrict__ wpw,
             const float* __restrict__ dmat, const float* __restrict__ invn_g,
             const float* __restrict__ beta_g, const float* __restrict__ bvec,
             float* __restrict__ out, unsigned* __restrict__ gcnt) {
    const int blk = blockIdx.x;
    const int whalf = blk & 1;
    const int h = (blk >> 1) & 31;
    const int b = blk >> 6;
    const int tid = threadIdx.x;
    const int lane = tid & 63;
    const int co = lane;
    const int wid = __builtin_amdgcn_readfirstlane(tid >> 6);   // 0..7
    const int w0 = whalf * 16 + wid * 2;        // global w of wave's pixel 0

    __shared__ float d_lds[4096];
    __shared__ unsigned long long msk[NSTEP][16];

    for (int i = tid; i < 4096; i += 512) d_lds[i] = dmat[i];
    {
        unsigned long long* mp = &msk[0][0];
        for (int i = tid; i < NSTEP * 16; i += 512) mp[i] = 0ull;
    }

    const float beta_v = beta_g[0];
    const float omb = 1.0f - beta_v;
    const float invn = invn_g[co];
    const float bth  = bvec[co];

    float wa[32];
#pragma unroll
    for (int ci = 0; ci < 32; ++ci) wa[ci] = wpw[co * 32 + ci];

    float mem0 = 0.f, mem1 = 0.f;
    unsigned long long m0p = 0ull, m1p = 0ull;

    // t = 0 plane: all spikes zero (inp=0, mem=0, -b<0). 512 thr x float2 = 4KB.
    {
        const int zco = tid >> 3, zw = (tid & 7) * 2;
        *(float2*)(out + ((size_t)(b * 64 + zco) * NSTEP) * NPIX + h * 32 + whalf * 16 + zw)
            = make_float2(0.f, 0.f);
    }

    __syncthreads();   // d_lds + zeroed bitplanes visible

    // wave-uniform base into dw2 (b, h-1, slots w0..w0+1); valid iff h>=1
    const int base0 = ((b * TT_) * 32 + (h - 1)) * NPIX + w0 * 32;
    const bool hok = (h >= 1);

    f32x16 A0, A1, A2, A3;          // wave-uniform -> SGPRs
    if (hok) {                      // preload step t=1 (plane 0)
        const float* wrow = dw2 + (size_t)base0;
        A0 = *(const f32x16*)(wrow);
        A1 = *(const f32x16*)(wrow + 16);
        A2 = *(const f32x16*)(wrow + 32);
        A3 = *(const f32x16*)(wrow + 48);
    }

    for (int t = 1; t < NSTEP; ++t) {
        float inp0 = 0.f, inp1 = 0.f;
        if (hok && t <= TT_) {      // consume current A set (ci-ascending, bit-exact)
#pragma unroll
            for (int ci = 0; ci < 16; ++ci) {
                inp0 = fmaf(wa[ci], A0[ci], inp0);
                inp1 = fmaf(wa[ci], A2[ci], inp1);
            }
#pragma unroll
            for (int ci = 0; ci < 16; ++ci) {
                inp0 = fmaf(wa[16 + ci], A1[ci], inp0);
                inp1 = fmaf(wa[16 + ci], A3[ci], inp1);
            }
        }
        // reissue loads for step t+1 into the same registers (hidden under tail)
        if (hok && t < TT_) {
            const float* wrow = dw2 + (size_t)base0 + (size_t)t * (32 * NPIX);
            A0 = *(const f32x16*)(wrow);
            A1 = *(const f32x16*)(wrow + 16);
            A2 = *(const f32x16*)(wrow + 32);
            A3 = *(const f32x16*)(wrow + 48);
        }

        // lateral reset from previous step's masks (sparse bit iteration)
        float rst0 = 0.f, rst1 = 0.f;
        unsigned long long mm = m0p;
        while (mm) { const int a = __builtin_ctzll(mm); mm &= mm - 1; rst0 += d_lds[a * 64 + co]; }
        mm = m1p;
        while (mm) { const int a = __builtin_ctzll(mm); mm &= mm - 1; rst1 += d_lds[a * 64 + co]; }

        // membrane update + spike (same expression order as validated rounds)
        const float u0 = (mem0 - rst0) * beta_v;
        mem0 = u0 + inp0 * omb;
        const bool s0 = (mem0 * invn - bth) > 0.f;
        const float u1 = (mem1 - rst1) * beta_v;
        mem1 = u1 + inp1 * omb;
        const bool s1 = (mem1 * invn - bth) > 0.f;

        m0p = __ballot(s0);
        m1p = __ballot(s1);
        const int wl = wid * 2;
        if (lane == 0) { msk[t][wl] = m0p; msk[t][wl + 1] = m1p; }
    }
    __syncthreads();

    // exact per-t spike counts (integer, deterministic)
    if (tid < NSTEP) {
        unsigned c = 0;
        for (int w = 0; w < 16; ++w) c += (unsigned)__popcll(msk[tid][w]);
        if (c) atomicAdd(&gcnt[tid], c);
    }

    // coalesced bit->float stores: 1408 (co,t) rows x 16 w (64B, sector-exact)
    const int wl = tid & 15;
    for (int it = 0; it < 44; ++it) {
        const int r = it * 32 + (tid >> 4);         // 0..1407
        const int tt = r >> 6, cc = r & 63;
        const unsigned long long wv = msk[tt][wl];
        const float sv = (float)((wv >> cc) & 1ull);
        out[((size_t)(b * 64 + cc) * NSTEP + tt) * NPIX + h * 32 + whalf * 16 + wl] = sv;
    }
}

// ---------------------------------------------------------------------------
// K4: losses from exact integer spike counts (separate 1-block launch:
// the kernel boundary IS the cheap device-wide fence).
// ---------------------------------------------------------------------------
__global__ void k_final(const unsigned* __restrict__ gcnt, float* __restrict__ out,
                        int out_size) {
    if (threadIdx.x == 0 && blockIdx.x == 0) {
        unsigned long long tot = 0; unsigned mx = 0;
        for (int t = 0; t < NSTEP; ++t) { const unsigned c = gcnt[t]; tot += c; if (c > mx) mx = c; }
        const long long nspk = (long long)out_size - 2;          // 23,068,672
        out[out_size - 2] = (float)(0.5 * ((double)tot / (double)nspk));
        out[out_size - 1] = (float)((double)mx / 1048576.0);     // / (B*COUT*H*W)
    }
}

extern "C" void kernel_launch(void* const* d_in, const int* in_sizes, int n_in,
                              void* d_out, int out_size, void* d_ws, size_t ws_size,
                              hipStream_t stream) {
    const float* x    = (const float*)d_in[0];
    const float* wdw  = (const float*)d_in[1];
    const float* wpw  = (const float*)d_in[2];
    const float* beta = (const float*)d_in[3];
    const float* bvec = (const float*)d_in[4];
    float* out = (float*)d_out;
    float* ws  = (float*)d_ws;

    if (ws_size < WS_FLOATS * sizeof(float)) return;

    float* dwout = ws + OFF_DWOUT;
    float* dw2   = ws + OFF_DW2;
    float* dmat  = ws + OFF_D;
    float* invn  = ws + OFF_INVN;
    unsigned* gcnt = (unsigned*)(ws + OFF_CNT);

    k_depthwise<<<DW_BLOCKS + 1, 128, 0, stream>>>(x, wdw, wpw, dwout, dmat, invn, gcnt);
    k_transpose<<<BB_ * TT_ * 8, 256, 0, stream>>>(dwout, dw2);
    k_recur    <<<BB_ * HW_ * 2, 512, 0, stream>>>(dw2, wpw, dmat, invn, beta, bvec, out, gcnt);
    k_final    <<<1, 64, 0, stream>>>(gcnt, out, out_size);
}

// Round 13
// 95.150 us; speedup vs baseline: 1.7531x; 1.0723x over previous
//
#include <hip/hip_runtime.h>

// Problem constants
#define BB_   16
#define CIN_  32
#define COUT_ 64
#define TT_   20      // depthwise time extent
#define NSTEP 22      // recurrence steps (pointwise pad grows T 20->22)
#define NPIX  1024    // 32*32
#define HW_   32

typedef float f32x16 __attribute__((ext_vector_type(16)));

// ws layout (in floats)
#define N_DWOUT 10485760ULL                    // 16*32*20*1024 [ci-major]
#define N_DW2   10485760ULL                    // 16*20*32*1024 [slot][ci] transposed
#define OFF_DWOUT 0ULL
#define OFF_DW2   (OFF_DWOUT + N_DWOUT)
#define OFF_D     (OFF_DW2 + N_DW2)            // 4096 floats
#define OFF_INVN  (OFF_D + 4096ULL)            // 64 floats
#define OFF_CNT   (OFF_INVN + 64ULL)           // 22 uint32
#define WS_FLOATS (OFF_CNT + 32ULL)

#define DW_BLOCKS (BB_ * CIN_ * 4)             // 2048 conv blocks; block 0 = dmat

// ---------------------------------------------------------------------------
// K1: depthwise 3x3x3 conv (R5 verbatim) + dmat side-block at BLOCK 0:
// dispatched first, the fp64 lateral-matrix block overlaps under the 2048
// conv blocks (R12 lesson: at the tail it serializes ~6-10us as a straggler).
// Conv blocks are blk-1. No device fences anywhere (R11 lesson).
// ---------------------------------------------------------------------------
__global__ __launch_bounds__(128)
void k_depthwise(const float* __restrict__ x, const float* __restrict__ wdw,
                 const float* __restrict__ wpw, float* __restrict__ dwout,
                 float* __restrict__ dmat, float* __restrict__ invn,
                 unsigned* __restrict__ gcnt) {
    const int blk = blockIdx.x;
    const int tid = threadIdx.x;

    if (blk == 0) {                            // ---- dmat block (first, overlapped)
        __shared__ double S[32];
        if (tid < NSTEP) gcnt[tid] = 0u;
        if (tid < 32) {
            double s = 0.0;
            for (int k = 0; k < 27; ++k) { double v = (double)wdw[tid * 27 + k]; s += v * v; }
            S[tid] = s;
        }
        __syncthreads();
        for (int e = tid; e < 4096; e += 128) {
            const int a = e >> 6, f = e & 63;
            double acc = 0.0;
            for (int ci = 0; ci < 32; ++ci)
                acc += (double)wpw[a * 32 + ci] * (double)wpw[f * 32 + ci] * S[ci];
            dmat[e] = (float)acc;
            if (a == f) invn[a] = (float)(1.0 / (acc + 1e-8));
        }
        return;
    }

    const int tile = blk - 1;                  // 0..2047
    const int t4 = tile & 3;
    const int ci = (tile >> 2) & 31;
    const int b  = tile >> 7;
    __shared__ float pl[3][34][35];

    float w[27];
#pragma unroll
    for (int k = 0; k < 27; ++k) w[k] = wdw[ci * 27 + k];

    for (int i = tid; i < 3 * 34 * 35; i += 128) (&pl[0][0][0])[i] = 0.f;
    __syncthreads();

    const float* xb = x + (size_t)(b * 32 + ci) * TT_ * NPIX;
    const int lr = tid >> 2;
    const int lc = (tid & 3) * 8;

    auto load_plane = [&](int p, int slot) {
        const float* s = xb + (size_t)p * NPIX + lr * 32 + lc;
        float4 v0 = *(const float4*)s;
        float4 v1 = *(const float4*)(s + 4);
        float* d = &pl[slot][1 + lr][1 + lc];
        d[0] = v0.x; d[1] = v0.y; d[2] = v0.z; d[3] = v0.w;
        d[4] = v1.x; d[5] = v1.y; d[6] = v1.z; d[7] = v1.w;
    };
    auto zero_plane = [&](int slot) {
        float* d = &pl[slot][1 + lr][1 + lc];
#pragma unroll
        for (int j = 0; j < 8; ++j) d[j] = 0.f;
    };

    const int T0 = t4 * 5;
    if (T0 > 0) load_plane(T0 - 1, (T0 - 1) % 3);
    load_plane(T0, T0 % 3);

    const int hd = lr, wd0 = lc;
    const float* base = &pl[0][0][0];

    for (int t = T0; t < T0 + 5; ++t) {
        __syncthreads();
        const int pnext = t + 1;
        if (pnext < TT_) load_plane(pnext, pnext % 3);
        else             zero_plane(pnext % 3);
        __syncthreads();

        const int sm1 = (t + 2) % 3, s0 = t % 3, sp1 = (t + 1) % 3;
        float acc[8] = {0.f,0.f,0.f,0.f,0.f,0.f,0.f,0.f};
#pragma unroll
        for (int kt = 0; kt < 3; ++kt) {
            const int slot = (kt == 0) ? sm1 : (kt == 1) ? s0 : sp1;
            const float* Pp = base + slot * (34 * 35);
#pragma unroll
            for (int kh = 0; kh < 3; ++kh) {
                const float* row = Pp + (hd + kh) * 35 + wd0;
                float r[10];
#pragma unroll
                for (int m = 0; m < 10; ++m) r[m] = row[m];
#pragma unroll
                for (int kw = 0; kw < 3; ++kw) {
                    const float wv = w[(kt * 3 + kh) * 3 + kw];
#pragma unroll
                    for (int j = 0; j < 8; ++j) acc[j] = fmaf(wv, r[j + kw], acc[j]);
                }
            }
        }
        float* dst = dwout + ((size_t)(b * 32 + ci) * TT_ + t) * NPIX + hd * 32 + wd0;
        *(float4*)dst       = make_float4(acc[0], acc[1], acc[2], acc[3]);
        *(float4*)(dst + 4) = make_float4(acc[4], acc[5], acc[6], acc[7]);
    }
}

// ---------------------------------------------------------------------------
// K2: transpose dwout -> dw2 [b][t][h][slot=w+1][ci], slot 0 = zeros.
// R5 verbatim. [slot][ci] layout is LOAD-BEARING: k_recur's per-step operands
// become 4 contiguous s_load_dwordx16 (R10: strided 8B scalar loads 3x slower).
// ---------------------------------------------------------------------------
__global__ __launch_bounds__(256)
void k_transpose(const float* __restrict__ dwout, float* __restrict__ dw2) {
    const int blk = blockIdx.x;            // (b*20 + t)*8 + hq
    const int hq = blk & 7;
    const int bt = blk >> 3;
    const int t  = bt % 20;
    const int b  = bt / 20;
    const int tid = threadIdx.x;
    __shared__ float lt[32][33];
    const int wsrc = tid & 31, cg = tid >> 5;

    for (int hh = 0; hh < 4; ++hh) {
        const int h = hq * 4 + hh;
#pragma unroll
        for (int cc = 0; cc < 4; ++cc) {
            const int ci = cc * 8 + cg;
            lt[wsrc][ci] = dwout[((size_t)(b * 32 + ci) * TT_ + t) * NPIX + h * 32 + wsrc];
        }
        __syncthreads();
        float* drow = dw2 + ((size_t)(b * TT_ + t) * 32 + h) * NPIX;
#pragma unroll
        for (int ss = 0; ss < 4; ++ss) {
            const int slot = ss * 8 + cg;
            drow[slot * 32 + wsrc] = (slot == 0) ? 0.f : lt[slot - 1][wsrc];
        }
        __syncthreads();
    }
}

// ---------------------------------------------------------------------------
// K3: ballot-wave fused pointwise conv + recurrence — R5 VERBATIM.
// ---------------------------------------------------------------------------
__global__ __launch_bounds__(512)
void k_recur(const float* __restrict__ dw2, const float* __restrict__ wpw,
             const float* __restrict__ dmat, const float* __restrict__ invn_g,
             const float* __restrict__ beta_g, const float* __restrict__ bvec,
             float* __restrict__ out, unsigned* __restrict__ gcnt) {
    const int blk = blockIdx.x;
    const int whalf = blk & 1;
    const int h = (blk >> 1) & 31;
    const int b = blk >> 6;
    const int tid = threadIdx.x;
    const int lane = tid & 63;
    const int co = lane;
    const int wid = __builtin_amdgcn_readfirstlane(tid >> 6);   // 0..7
    const int w0 = whalf * 16 + wid * 2;        // global w of wave's pixel 0

    __shared__ float d_lds[4096];
    __shared__ unsigned long long msk[NSTEP][16];

    for (int i = tid; i < 4096; i += 512) d_lds[i] = dmat[i];
    {
        unsigned long long* mp = &msk[0][0];
        for (int i = tid; i < NSTEP * 16; i += 512) mp[i] = 0ull;
    }

    const float beta_v = beta_g[0];
    const float omb = 1.0f - beta_v;
    const float invn = invn_g[co];
    const float bth  = bvec[co];

    float wa[32];
#pragma unroll
    for (int ci = 0; ci < 32; ++ci) wa[ci] = wpw[co * 32 + ci];

    float mem0 = 0.f, mem1 = 0.f;
    unsigned long long m0p = 0ull, m1p = 0ull;

    // t = 0 plane: all spikes zero (inp=0, mem=0, -b<0). 512 thr x float2 = 4KB.
    {
        const int zco = tid >> 3, zw = (tid & 7) * 2;
        *(float2*)(out + ((size_t)(b * 64 + zco) * NSTEP) * NPIX + h * 32 + whalf * 16 + zw)
            = make_float2(0.f, 0.f);
    }

    __syncthreads();   // d_lds + zeroed bitplanes visible

    // wave-uniform base into dw2 (b, h-1, slots w0..w0+1); valid iff h>=1
    const int base0 = ((b * TT_) * 32 + (h - 1)) * NPIX + w0 * 32;
    const bool hok = (h >= 1);

    f32x16 A0, A1, A2, A3;          // wave-uniform -> SGPRs
    if (hok) {                      // preload step t=1 (plane 0)
        const float* wrow = dw2 + (size_t)base0;
        A0 = *(const f32x16*)(wrow);
        A1 = *(const f32x16*)(wrow + 16);
        A2 = *(const f32x16*)(wrow + 32);
        A3 = *(const f32x16*)(wrow + 48);
    }

    for (int t = 1; t < NSTEP; ++t) {
        float inp0 = 0.f, inp1 = 0.f;
        if (hok && t <= TT_) {      // consume current A set (ci-ascending, bit-exact)
#pragma unroll
            for (int ci = 0; ci < 16; ++ci) {
                inp0 = fmaf(wa[ci], A0[ci], inp0);
                inp1 = fmaf(wa[ci], A2[ci], inp1);
            }
#pragma unroll
            for (int ci = 0; ci < 16; ++ci) {
                inp0 = fmaf(wa[16 + ci], A1[ci], inp0);
                inp1 = fmaf(wa[16 + ci], A3[ci], inp1);
            }
        }
        // reissue loads for step t+1 into the same registers (hidden under tail)
        if (hok && t < TT_) {
            const float* wrow = dw2 + (size_t)base0 + (size_t)t * (32 * NPIX);
            A0 = *(const f32x16*)(wrow);
            A1 = *(const f32x16*)(wrow + 16);
            A2 = *(const f32x16*)(wrow + 32);
            A3 = *(const f32x16*)(wrow + 48);
        }

        // lateral reset from previous step's masks (sparse bit iteration)
        float rst0 = 0.f, rst1 = 0.f;
        unsigned long long mm = m0p;
        while (mm) { const int a = __builtin_ctzll(mm); mm &= mm - 1; rst0 += d_lds[a * 64 + co]; }
        mm = m1p;
        while (mm) { const int a = __builtin_ctzll(mm); mm &= mm - 1; rst1 += d_lds[a * 64 + co]; }

        // membrane update + spike (same expression order as validated rounds)
        const float u0 = (mem0 - rst0) * beta_v;
        mem0 = u0 + inp0 * omb;
        const bool s0 = (mem0 * invn - bth) > 0.f;
        const float u1 = (mem1 - rst1) * beta_v;
        mem1 = u1 + inp1 * omb;
        const bool s1 = (mem1 * invn - bth) > 0.f;

        m0p = __ballot(s0);
        m1p = __ballot(s1);
        const int wl = wid * 2;
        if (lane == 0) { msk[t][wl] = m0p; msk[t][wl + 1] = m1p; }
    }
    __syncthreads();

    // exact per-t spike counts (integer, deterministic)
    if (tid < NSTEP) {
        unsigned c = 0;
        for (int w = 0; w < 16; ++w) c += (unsigned)__popcll(msk[tid][w]);
        if (c) atomicAdd(&gcnt[tid], c);
    }

    // coalesced bit->float stores: 1408 (co,t) rows x 16 w (64B, sector-exact)
    const int wl = tid & 15;
    for (int it = 0; it < 44; ++it) {
        const int r = it * 32 + (tid >> 4);         // 0..1407
        const int tt = r >> 6, cc = r & 63;
        const unsigned long long wv = msk[tt][wl];
        const float sv = (float)((wv >> cc) & 1ull);
        out[((size_t)(b * 64 + cc) * NSTEP + tt) * NPIX + h * 32 + whalf * 16 + wl] = sv;
    }
}

// ---------------------------------------------------------------------------
// K4: losses from exact integer spike counts (separate 1-block launch:
// the kernel boundary IS the cheap device-wide fence).
// ---------------------------------------------------------------------------
__global__ void k_final(const unsigned* __restrict__ gcnt, float* __restrict__ out,
                        int out_size) {
    if (threadIdx.x == 0 && blockIdx.x == 0) {
        unsigned long long tot = 0; unsigned mx = 0;
        for (int t = 0; t < NSTEP; ++t) { const unsigned c = gcnt[t]; tot += c; if (c > mx) mx = c; }
        const long long nspk = (long long)out_size - 2;          // 23,068,672
        out[out_size - 2] = (float)(0.5 * ((double)tot / (double)nspk));
        out[out_size - 1] = (float)((double)mx / 1048576.0);     // / (B*COUT*H*W)
    }
}

extern "C" void kernel_launch(void* const* d_in, const int* in_sizes, int n_in,
                              void* d_out, int out_size, void* d_ws, size_t ws_size,
                              hipStream_t stream) {
    const float* x    = (const float*)d_in[0];
    const float* wdw  = (const float*)d_in[1];
    const float* wpw  = (const float*)d_in[2];
    const float* beta = (const float*)d_in[3];
    const float* bvec = (const float*)d_in[4];
    float* out = (float*)d_out;
    float* ws  = (float*)d_ws;

    if (ws_size < WS_FLOATS * sizeof(float)) return;

    float* dwout = ws + OFF_DWOUT;
    float* dw2   = ws + OFF_DW2;
    float* dmat  = ws + OFF_D;
    float* invn  = ws + OFF_INVN;
    unsigned* gcnt = (unsigned*)(ws + OFF_CNT);

    k_depthwise<<<DW_BLOCKS + 1, 128, 0, stream>>>(x, wdw, wpw, dwout, dmat, invn, gcnt);
    k_transpose<<<BB_ * TT_ * 8, 256, 0, stream>>>(dwout, dw2);
    k_recur    <<<BB_ * HW_ * 2, 512, 0, stream>>>(dw2, wpw, dmat, invn, beta, bvec, out, gcnt);
    k_final    <<<1, 64, 0, stream>>>(gcnt, out, out_size);
}